// Round 4
// baseline (2144.506 us; speedup 1.0000x reference)
//
#include <hip/hip_runtime.h>

namespace {
constexpr int T    = 2048;
constexpr int Bsz  = 4096;
constexpr int H    = 51;     // hidden units
constexpr int H4   = 204;    // 4*H gate rows
constexpr int NB   = 16;     // batches per block = MFMA free dim
constexpr int BLK  = 512;    // 8 waves
constexpr int GRID = Bsz / NB;  // 256 blocks = 1/CU
constexpr float SCI = -1.44269504f;   // -log2(e), gates i,f,o
constexpr float SCG = -2.88539008f;   // -2*log2(e), gate g
}

typedef float    f32x4 __attribute__((ext_vector_type(4)));
typedef _Float16 f16x8 __attribute__((ext_vector_type(8)));
typedef unsigned short u16;

__device__ __forceinline__ float RCP(float x)  { return __builtin_amdgcn_rcpf(x); }
__device__ __forceinline__ float EXP2(float x) { return __builtin_amdgcn_exp2f(x); }

// Inputs pre-scaled: Gi=-log2e*gi, Gf=-log2e*gf, Gg=-2log2e*gg, Go=-log2e*go
// c = sigm(f)*c + sigm(i)*tanh(g) via single rcp; h = sigm(o)*tanh(c).
__device__ __forceinline__ float lstm_act(float Gi, float Gf, float Gg, float Go, float& c) {
  float ei = EXP2(Gi);
  float ef = EXP2(Gf);
  float eo = EXP2(Go);
  float eg = EXP2(-fabsf(Gg));
  float pi = 1.0f + ei, pf = 1.0f + ef, pg = 1.0f + eg;
  float tg = copysignf(1.0f - eg, -Gg);        // sign(gg)*(1-eg)
  float pig = pi * pg;
  float num = fmaf(c, pig, tg * pf);
  c = num * RCP(pig * pf);
  float ec = EXP2(SCG * fabsf(c));
  float tc = copysignf(1.0f - ec, c);
  return tc * RCP((1.0f + eo) * (1.0f + ec));
}

// Fragment k-mapping (validated r2/r3, same for A and B sides):
//   lane = free(0..15) + 16*q ; elem j: k = 32*sp + 16*(j>>2) + 4*q + (j&3)
// h-plane slot for (b,k): sp=k>>5, kl=k&31, row=b+16*((kl>>2)&3), j=(kl&3)+4*(kl>>4)
// PL shorts: [buf(2)][layer(2)][sp(2)][row(64)][j(8)] = 4096 shorts = 8KB
// L1 k-slots: k<51 h1 | 51 x0 | 52 x1 | 53 const1 ; L2 (k-64): <51 h2 | 53 const1

__global__ __launch_bounds__(BLK, 2) void lstm2_v4(
    const float* __restrict__ x,
    const float* __restrict__ Wih1, const float* __restrict__ Whh1,
    const float* __restrict__ bih1, const float* __restrict__ bhh1,
    const float* __restrict__ Wih2, const float* __restrict__ Whh2,
    const float* __restrict__ bih2, const float* __restrict__ bhh2,
    const float* __restrict__ Wlin, const float* __restrict__ blin,
    float* __restrict__ out) {
  __shared__ __align__(16) float  SW[H4 * H];      // 41.6 KB weight staging (init only)
  __shared__ __align__(16) u16    PL[4096];        // 8 KB h-plane ping-pong
  __shared__ __align__(16) float2 XB[2][32][16];   // 8 KB x chunk double-buffer
  __shared__ __align__(16) float  OB[2][16][33];   // 4.1 KB out chunk (pad 33 vs conflicts)

  const int tid  = threadIdx.x;
  const int lane = tid & 63;
  const int wid  = tid >> 6;
  const int a    = lane & 15;
  const int q    = lane >> 4;
  const int b0   = blockIdx.x * NB;

  int t0 = -1, t1 = -1;
  switch (wid) {
    case 0: t0 = 0;  t1 = 1;  break;
    case 1: t0 = 4;  t1 = 5;  break;
    case 2: t0 = 7;  t1 = 8;  break;
    case 3: t0 = 10; t1 = 11; break;
    case 4: t0 = 2;  t1 = 3;  break;
    case 5: t0 = 6;  break;
    case 6: t0 = 9;  break;
    case 7: t0 = 12; break;
  }
  const bool isHead = (wid == 7);

  // ---------------- init: weight A-fragments (pre-scaled, hi/lo fp16) ----------------
  f16x8 wA1[2][2][2];   // [tile][sp][hi/lo]
  f16x8 wA2[2][4][2];
  f16x8 hA[2][2];

  for (int i = tid; i < H4 * H; i += BLK) SW[i] = Whh1[i];
  __syncthreads();
#pragma unroll
  for (int i = 0; i < 2; ++i) {
    const int tt = (i == 0) ? t0 : t1;
    if (tt >= 0) {
      const int  rp   = 16 * tt + a;
      const bool vld  = (rp < H4);
      const int  gate = rp & 3;
      const int  wrow = gate * H + (rp >> 2);
      const float sc  = (gate == 2) ? SCG : SCI;
#pragma unroll
      for (int sp = 0; sp < 2; ++sp)
#pragma unroll
        for (int j = 0; j < 8; ++j) {
          const int k = 32 * sp + 16 * (j >> 2) + 4 * q + (j & 3);
          float val = 0.f;
          if (vld) {
            if (k < H)           val = SW[wrow * H + k];
            else if (k == H)     val = Wih1[wrow * 2 + 0];
            else if (k == H + 1) val = Wih1[wrow * 2 + 1];
            else if (k == H + 2) val = bih1[wrow] + bhh1[wrow];
          }
          val *= sc;
          const _Float16 hi = (_Float16)val;
          wA1[i][sp][0][j] = hi;
          wA1[i][sp][1][j] = (_Float16)(val - (float)hi);
        }
    }
  }
  __syncthreads();
  for (int i = tid; i < H4 * H; i += BLK) SW[i] = Wih2[i];
  __syncthreads();
#pragma unroll
  for (int i = 0; i < 2; ++i) {
    const int tt = (i == 0) ? t0 : t1;
    if (tt >= 0) {
      const int  rp   = 16 * tt + a;
      const bool vld  = (rp < H4);
      const int  gate = rp & 3;
      const int  wrow = gate * H + (rp >> 2);
      const float sc  = (gate == 2) ? SCG : SCI;
#pragma unroll
      for (int sp = 0; sp < 2; ++sp)
#pragma unroll
        for (int j = 0; j < 8; ++j) {
          const int k = 32 * sp + 16 * (j >> 2) + 4 * q + (j & 3);
          float val = 0.f;
          if (vld) {
            if (k < H)           val = SW[wrow * H + k];
            else if (k == H + 2) val = bih2[wrow] + bhh2[wrow];
          }
          val *= sc;
          const _Float16 hi = (_Float16)val;
          wA2[i][sp][0][j] = hi;
          wA2[i][sp][1][j] = (_Float16)(val - (float)hi);
        }
    }
  }
  __syncthreads();
  for (int i = tid; i < H4 * H; i += BLK) SW[i] = Whh2[i];
  __syncthreads();
#pragma unroll
  for (int i = 0; i < 2; ++i) {
    const int tt = (i == 0) ? t0 : t1;
    if (tt >= 0) {
      const int  rp   = 16 * tt + a;
      const bool vld  = (rp < H4);
      const int  gate = rp & 3;
      const int  wrow = gate * H + (rp >> 2);
      const float sc  = (gate == 2) ? SCG : SCI;
#pragma unroll
      for (int sp = 2; sp < 4; ++sp)
#pragma unroll
        for (int j = 0; j < 8; ++j) {
          const int kp = 32 * (sp - 2) + 16 * (j >> 2) + 4 * q + (j & 3);
          float val = (vld && kp < H) ? SW[wrow * H + kp] * sc : 0.f;
          const _Float16 hi = (_Float16)val;
          wA2[i][sp][0][j] = hi;
          wA2[i][sp][1][j] = (_Float16)(val - (float)hi);
        }
    }
  }
  if (isHead) {   // head fragments (row 0), unscaled
#pragma unroll
    for (int sp = 0; sp < 2; ++sp)
#pragma unroll
      for (int j = 0; j < 8; ++j) {
        const int kp = 32 * sp + 16 * (j >> 2) + 4 * q + (j & 3);
        float val = 0.f;
        if (a == 0) {
          if (kp < H)           val = Wlin[kp];
          else if (kp == H + 2) val = blin[0];
        }
        const _Float16 hi = (_Float16)val;
        hA[sp][0][j] = hi;
        hA[sp][1][j] = (_Float16)(val - (float)hi);
      }
  }

  // ---------------- init planes, x chunk 0, x(0) injection ----------------
  __syncthreads();
  for (int i = tid; i < 4096; i += BLK) PL[i] = 0;
  __syncthreads();
  if (tid < 16) {
#pragma unroll
    for (int buf = 0; buf < 2; ++buf) {
      PL[(buf * 4 + 0 * 2 + 1) * 512 + (tid + 16) * 8 + 5] = 0x3C00;  // fp16 1.0
      PL[(buf * 4 + 1 * 2 + 1) * 512 + (tid + 16) * 8 + 5] = 0x3C00;
    }
  }
  {  // preload x chunk 0 (steps 0..31)
    const int step = tid >> 4, bi = tid & 15;
    XB[0][step][bi] = *(const float2*)(x + ((size_t)step * Bsz + b0 + bi) * 2);
  }
  __syncthreads();
  if (isHead && lane < 32) {  // x(0) -> plane buf0
    const int bb = lane & 15, f = lane >> 4;
    const float xv = ((const float*)&XB[0][0][bb])[f];
    const int idx = (0 * 4 + 0 * 2 + 1) * 512 + ((f == 0) ? bb * 8 + 7 : (bb + 16) * 8 + 4);
    *(_Float16*)&PL[idx] = (_Float16)xv;
  }
  __syncthreads();

  // ---------------- main loop ----------------
  float c1[2] = {0.f, 0.f}, c2[2] = {0.f, 0.f};
  float2 xcr = {0.f, 0.f};   // chunk-load staging reg

  for (int s = 0; s < T + 3; ++s) {
    const int pb = (s & 1) * 2048;
    const int nb = 2048 - pb;

    f16x8 bh[4];
#pragma unroll
    for (int p = 0; p < 4; ++p)
      bh[p] = *(const f16x8*)&PL[pb + p * 512 + lane * 8];

    // ---- x chunk pipeline: issue loads at chunk start, LDS-write next slot ----
    if ((s & 31) == 0) {
      if (s + 32 < T) {
        const int step = s + 32 + (tid >> 4), bi = tid & 15;
        xcr = *(const float2*)(x + ((size_t)step * Bsz + b0 + bi) * 2);
      }
    } else if ((s & 31) == 1) {
      if (s + 31 < T) {
        const int buf = ((s >> 5) + 1) & 1;
        XB[buf][tid >> 4][tid & 15] = xcr;
      }
    } else if ((s & 31) == 2) {
      if (s >= 34) {  // flush out chunk f = (s-34)>>5
        const int f = (s - 34) >> 5;
        if (tid < 128) {
          const int b = tid >> 3, g = tid & 7;
          const float4 v = *(const float4*)&OB[f & 1][b][g * 4];
          *(float4*)(out + (size_t)(b0 + b) * T + f * 32 + g * 4) = v;
        }
      }
    }

    // ---- MFMA (hi/lo parallel chains) ----
    f32x4 d1[2], d2[2];
#pragma unroll
    for (int i = 0; i < 2; ++i) {
      const int tt = (i == 0) ? t0 : t1;
      if (tt >= 0) {
        f32x4 aH = {0.f,0.f,0.f,0.f}, aL = {0.f,0.f,0.f,0.f};
#pragma unroll
        for (int sp = 0; sp < 2; ++sp) {
          aH = __builtin_amdgcn_mfma_f32_16x16x32_f16(wA1[i][sp][0], bh[sp], aH, 0, 0, 0);
          aL = __builtin_amdgcn_mfma_f32_16x16x32_f16(wA1[i][sp][1], bh[sp], aL, 0, 0, 0);
        }
        d1[i] = aH + aL;
        f32x4 bH = {0.f,0.f,0.f,0.f}, bL = {0.f,0.f,0.f,0.f};
#pragma unroll
        for (int sp = 0; sp < 4; ++sp) {
          bH = __builtin_amdgcn_mfma_f32_16x16x32_f16(wA2[i][sp][0], bh[sp], bH, 0, 0, 0);
          bL = __builtin_amdgcn_mfma_f32_16x16x32_f16(wA2[i][sp][1], bh[sp], bL, 0, 0, 0);
        }
        d2[i] = bH + bL;
      }
    }

    // ---- activations + h-plane writes ----
    const bool doA1 = (s < T);
    const bool doA2 = (s >= 1 && s <= T);
#pragma unroll
    for (int i = 0; i < 2; ++i) {
      const int tt = (i == 0) ? t0 : t1;
      if (tt >= 0) {
        const int  u    = 4 * tt + q;
        const bool uval = (u < H);
        const int  spl  = u >> 5, kl = u & 31;
        const int  row  = a + 16 * ((kl >> 2) & 3);
        const int  jj   = (kl & 3) + 4 * (kl >> 4);
        const int  widx = nb + spl * 512 + row * 8 + jj;
        if (doA1) {
          const float h1 = lstm_act(d1[i][0], d1[i][1], d1[i][2], d1[i][3], c1[i]);
          if (uval) *(_Float16*)&PL[widx] = (_Float16)h1;
        }
        if (doA2) {
          const float h2 = lstm_act(d2[i][0], d2[i][1], d2[i][2], d2[i][3], c2[i]);
          if (uval) *(_Float16*)&PL[widx + 1024] = (_Float16)h2;
        }
      }
    }

    // ---- head: out(s-2) -> OB ; x(s+1) -> plane ----
    if (isHead) {
      f32x4 dh = {0.f,0.f,0.f,0.f};
      dh = __builtin_amdgcn_mfma_f32_16x16x32_f16(hA[0][0], bh[2], dh, 0, 0, 0);
      dh = __builtin_amdgcn_mfma_f32_16x16x32_f16(hA[0][1], bh[2], dh, 0, 0, 0);
      dh = __builtin_amdgcn_mfma_f32_16x16x32_f16(hA[1][0], bh[3], dh, 0, 0, 0);
      dh = __builtin_amdgcn_mfma_f32_16x16x32_f16(hA[1][1], bh[3], dh, 0, 0, 0);
      if (s >= 2 && s - 2 < T && lane < 16)
        OB[((s - 2) >> 5) & 1][lane][(s - 2) & 31] = dh[0];
      if (lane < 32 && s + 1 < T) {
        const int bb = lane & 15, f = lane >> 4;
        const int st = (s + 1) & 31, cb = ((s + 1) >> 5) & 1;
        const float xv = ((const float*)&XB[cb][st][bb])[f];
        const int idx = nb + 512 + ((f == 0) ? bb * 8 + 7 : (bb + 16) * 8 + 4);
        *(_Float16*)&PL[idx] = (_Float16)xv;
      }
    }
    __syncthreads();
  }
}

extern "C" void kernel_launch(void* const* d_in, const int* in_sizes, int n_in,
                              void* d_out, int out_size, void* d_ws, size_t ws_size,
                              hipStream_t stream) {
  (void)in_sizes; (void)n_in; (void)d_ws; (void)ws_size; (void)out_size;
  const float* x    = (const float*)d_in[0];
  const float* Wih1 = (const float*)d_in[1];
  const float* Whh1 = (const float*)d_in[2];
  const float* bih1 = (const float*)d_in[3];
  const float* bhh1 = (const float*)d_in[4];
  const float* Wih2 = (const float*)d_in[5];
  const float* Whh2 = (const float*)d_in[6];
  const float* bih2 = (const float*)d_in[7];
  const float* bhh2 = (const float*)d_in[8];
  const float* Wlin = (const float*)d_in[9];
  const float* blin = (const float*)d_in[10];
  float* out = (float*)d_out;

  hipLaunchKernelGGL(lstm2_v4, dim3(GRID), dim3(BLK), 0, stream,
                     x, Wih1, Whh1, bih1, bhh1, Wih2, Whh2, bih2, bhh2,
                     Wlin, blin, out);
}

// Round 5
// 1359.755 us; speedup vs baseline: 1.5771x; 1.5771x over previous
//
#include <hip/hip_runtime.h>

namespace {
constexpr int T    = 2048;
constexpr int Bsz  = 4096;
constexpr int H    = 51;     // hidden units
constexpr int H4   = 204;    // 4*H gate rows
constexpr int NB   = 16;     // batches per block = MFMA free dim
constexpr int BLK  = 1024;   // 16 waves, 4 per SIMD
constexpr int GRID = Bsz / NB;  // 256 blocks = 1/CU
constexpr float SCI = -1.44269504f;   // -log2(e), gates i,f,o
constexpr float SCG = -2.88539008f;   // -2*log2(e), gate g
}

typedef float    f32x4 __attribute__((ext_vector_type(4)));
typedef _Float16 f16x8 __attribute__((ext_vector_type(8)));
typedef unsigned short u16;

__device__ __forceinline__ float RCP(float x)  { return __builtin_amdgcn_rcpf(x); }
__device__ __forceinline__ float EXP2(float x) { return __builtin_amdgcn_exp2f(x); }

// Inputs pre-scaled: Gi=-log2e*gi, Gf=-log2e*gf, Gg=-2log2e*gg, Go=-log2e*go
__device__ __forceinline__ float lstm_act(float Gi, float Gf, float Gg, float Go, float& c) {
  float ei = EXP2(Gi);
  float ef = EXP2(Gf);
  float eo = EXP2(Go);
  float eg = EXP2(-fabsf(Gg));
  float pi = 1.0f + ei, pf = 1.0f + ef, pg = 1.0f + eg;
  float tg = copysignf(1.0f - eg, -Gg);
  float pig = pi * pg;
  float num = fmaf(c, pig, tg * pf);
  c = num * RCP(pig * pf);
  float ec = EXP2(SCG * fabsf(c));
  float tc = copysignf(1.0f - ec, c);
  return tc * RCP((1.0f + eo) * (1.0f + ec));
}

// Fragment k-map (validated r2-r4): lane = free(0..15)+16*q ; elem j: k = 32*sp+16*(j>>2)+4*q+(j&3)
// h-plane slot (b,k): sp=k>>5, kl=k&31, row=b+16*((kl>>2)&3), j=(kl&3)+4*(kl>>4)
// PL shorts: [buf(2)][layer(2)][sp(2)][row(64)][j(8)] = 4096 shorts = 8KB
// L1 k-slots: k<51 h1 | 51 x0 | 52 x1 | 53 const1 ; L2 (k-64): <51 h2 | 53 const1

__global__ __launch_bounds__(BLK, 4) void lstm2_v5(
    const float* __restrict__ x,
    const float* __restrict__ Wih1, const float* __restrict__ Whh1,
    const float* __restrict__ bih1, const float* __restrict__ bhh1,
    const float* __restrict__ Wih2, const float* __restrict__ Whh2,
    const float* __restrict__ bih2, const float* __restrict__ bhh2,
    const float* __restrict__ Wlin, const float* __restrict__ blin,
    float* __restrict__ out) {
  __shared__ __align__(16) float  SW[H4 * H];      // 41.6 KB staging (init only)
  __shared__ __align__(16) u16    PL[4096];        // 8 KB h-plane ping-pong
  __shared__ __align__(16) float2 XB[2][32][16];   // 8 KB x chunk double-buffer
  __shared__ __align__(16) float  OB[2][16][33];   // 4.2 KB out chunk

  const int tid  = threadIdx.x;
  const int lane = tid & 63;
  const int wid  = tid >> 6;
  const int a    = lane & 15;
  const int q    = lane >> 4;
  const int b0   = blockIdx.x * NB;
  const int lt   = tid - 768;                      // chore lane (waves 12-15)

  // task assignment: balanced 7/7/6/6 acts per SIMD
  const int  l1t    = (wid <= 12) ? wid : -1;                      // L1 tiles 0..12
  const int  l2t    = (wid < 12) ? wid : ((wid == 13) ? 12 : -1);  // L2 tiles 0..12
  const bool isHead = (wid == 14);
  const bool isXinj = (wid == 15);

  // ---------------- init: weight A-fragments (pre-scaled single fp16) ----------------
  f16x8 wA1[2];     // L1: Whh1 | Wih1 cols | bias1   (K=64)
  f16x8 wA2[4];     // L2: sp0-1 Wih2+bias2, sp2-3 Whh2 (K=128)
  f16x8 hA[2][2];   // head: Wlin+blin, hi/lo kept (output-critical)

  for (int i = tid; i < H4 * H; i += BLK) SW[i] = Whh1[i];
  __syncthreads();
  if (l1t >= 0) {
    const int  rp   = 16 * l1t + a;
    const bool vld  = (rp < H4);
    const int  gate = rp & 3;
    const int  wrow = gate * H + (rp >> 2);
    const float sc  = (gate == 2) ? SCG : SCI;
#pragma unroll
    for (int sp = 0; sp < 2; ++sp)
#pragma unroll
      for (int j = 0; j < 8; ++j) {
        const int k = 32 * sp + 16 * (j >> 2) + 4 * q + (j & 3);
        float val = 0.f;
        if (vld) {
          if (k < H)           val = SW[wrow * H + k];
          else if (k == H)     val = Wih1[wrow * 2 + 0];
          else if (k == H + 1) val = Wih1[wrow * 2 + 1];
          else if (k == H + 2) val = bih1[wrow] + bhh1[wrow];
        }
        wA1[sp][j] = (_Float16)(val * sc);
      }
  }
  __syncthreads();
  for (int i = tid; i < H4 * H; i += BLK) SW[i] = Wih2[i];
  __syncthreads();
  if (l2t >= 0) {
    const int  rp   = 16 * l2t + a;
    const bool vld  = (rp < H4);
    const int  gate = rp & 3;
    const int  wrow = gate * H + (rp >> 2);
    const float sc  = (gate == 2) ? SCG : SCI;
#pragma unroll
    for (int sp = 0; sp < 2; ++sp)
#pragma unroll
      for (int j = 0; j < 8; ++j) {
        const int k = 32 * sp + 16 * (j >> 2) + 4 * q + (j & 3);
        float val = 0.f;
        if (vld) {
          if (k < H)           val = SW[wrow * H + k];
          else if (k == H + 2) val = bih2[wrow] + bhh2[wrow];
        }
        wA2[sp][j] = (_Float16)(val * sc);
      }
  }
  __syncthreads();
  for (int i = tid; i < H4 * H; i += BLK) SW[i] = Whh2[i];
  __syncthreads();
  if (l2t >= 0) {
    const int  rp   = 16 * l2t + a;
    const bool vld  = (rp < H4);
    const int  gate = rp & 3;
    const int  wrow = gate * H + (rp >> 2);
    const float sc  = (gate == 2) ? SCG : SCI;
#pragma unroll
    for (int sp = 2; sp < 4; ++sp)
#pragma unroll
      for (int j = 0; j < 8; ++j) {
        const int kp = 32 * (sp - 2) + 16 * (j >> 2) + 4 * q + (j & 3);
        float val = (vld && kp < H) ? SW[wrow * H + kp] * sc : 0.f;
        wA2[sp][j] = (_Float16)val;
      }
  }
  if (isHead) {
#pragma unroll
    for (int sp = 0; sp < 2; ++sp)
#pragma unroll
      for (int j = 0; j < 8; ++j) {
        const int kp = 32 * sp + 16 * (j >> 2) + 4 * q + (j & 3);
        float val = 0.f;
        if (a == 0) {
          if (kp < H)           val = Wlin[kp];
          else if (kp == H + 2) val = blin[0];
        }
        const _Float16 hi = (_Float16)val;
        hA[sp][0][j] = hi;
        hA[sp][1][j] = (_Float16)(val - (float)hi);
      }
  }

  // ---------------- init planes + x chunk 0 ----------------
  __syncthreads();
  for (int i = tid; i < 4096; i += BLK) PL[i] = 0;
  __syncthreads();
  if (tid < 16) {
#pragma unroll
    for (int buf = 0; buf < 2; ++buf) {
      PL[(buf * 4 + 1) * 512 + (tid + 16) * 8 + 5] = 0x3C00;  // L1 const-1 (fp16 1.0)
      PL[(buf * 4 + 3) * 512 + (tid + 16) * 8 + 5] = 0x3C00;  // L2 const-1
    }
  }
  if (lt >= 0) {  // preload x chunk 0 (steps 0..31): 256 lanes x float4
    const int st = lt >> 3, bc = (lt & 7) * 2;
    *(float4*)&XB[0][st][bc] = *(const float4*)(x + ((size_t)st * Bsz + b0 + bc) * 2);
  }
  __syncthreads();
  if (isXinj && lane < 32) {  // inject x(0) into plane buf0
    const int bb = lane & 15, f = lane >> 4;
    const float xv = ((const float*)&XB[0][0][0])[bb * 2 + f];
    const int idx = 512 + ((f == 0) ? bb * 8 + 7 : (bb + 16) * 8 + 4);
    *(_Float16*)&PL[idx] = (_Float16)xv;
  }
  __syncthreads();

  // precomputed plane-write slots
  int wbase1 = 0, wbase2 = 0;
  bool uval1 = false, uval2 = false;
  if (l1t >= 0) {
    const int u = 4 * l1t + q; uval1 = (u < H);
    const int spl = u >> 5, kl = u & 31;
    wbase1 = spl * 512 + (a + 16 * ((kl >> 2) & 3)) * 8 + ((kl & 3) + 4 * (kl >> 4));
  }
  if (l2t >= 0) {
    const int u = 4 * l2t + q; uval2 = (u < H);
    const int spl = u >> 5, kl = u & 31;
    wbase2 = 1024 + spl * 512 + (a + 16 * ((kl >> 2) & 3)) * 8 + ((kl & 3) + 4 * (kl >> 4));
  }

  float c1 = 0.f, c2 = 0.f;
  float4 xcr = {0.f, 0.f, 0.f, 0.f};

  for (int s = 0; s < T + 3; ++s) {
    const int pb   = (s & 1) * 2048;
    const int nbuf = 2048 - pb;

    // B-fragment reads (only what the wave's tasks need)
    f16x8 bh0, bh1, bh2, bh3;
    if (l1t >= 0 || l2t >= 0) {
      bh0 = *(const f16x8*)&PL[pb + lane * 8];
      bh1 = *(const f16x8*)&PL[pb + 512 + lane * 8];
    }
    if (l2t >= 0 || isHead) {
      bh2 = *(const f16x8*)&PL[pb + 1024 + lane * 8];
      bh3 = *(const f16x8*)&PL[pb + 1536 + lane * 8];
    }

    // chores (waves 12-15): x chunk load / LDS write / out flush
    if (lt >= 0) {
      const int ph = s & 31;
      if (ph == 0) {
        if (s + 32 < T) {
          const int st = lt >> 3, bc = (lt & 7) * 2;
          xcr = *(const float4*)(x + ((size_t)(s + 32 + st) * Bsz + b0 + bc) * 2);
        }
      } else if (ph == 1) {
        if (s + 31 < T) {
          const int buf = ((s >> 5) + 1) & 1;
          const int st = lt >> 3, bc = (lt & 7) * 2;
          *(float4*)&XB[buf][st][bc] = xcr;
        }
      } else if (ph == 2 && s >= 34) {
        const int f = (s - 34) >> 5;
        const int row = lt >> 4, c0 = (lt & 15) * 2;
        const float2 v = *(const float2*)&OB[f & 1][row][c0];
        *(float2*)(out + (size_t)(b0 + row) * T + f * 32 + c0) = v;
      }
    }

    // MFMA
    f32x4 d1, d2;
    if (l1t >= 0) {
      f32x4 acc = {0.f, 0.f, 0.f, 0.f};
      acc = __builtin_amdgcn_mfma_f32_16x16x32_f16(wA1[0], bh0, acc, 0, 0, 0);
      acc = __builtin_amdgcn_mfma_f32_16x16x32_f16(wA1[1], bh1, acc, 0, 0, 0);
      d1 = acc;
    }
    if (l2t >= 0) {
      f32x4 acc = {0.f, 0.f, 0.f, 0.f};
      acc = __builtin_amdgcn_mfma_f32_16x16x32_f16(wA2[0], bh0, acc, 0, 0, 0);
      acc = __builtin_amdgcn_mfma_f32_16x16x32_f16(wA2[1], bh1, acc, 0, 0, 0);
      acc = __builtin_amdgcn_mfma_f32_16x16x32_f16(wA2[2], bh2, acc, 0, 0, 0);
      acc = __builtin_amdgcn_mfma_f32_16x16x32_f16(wA2[3], bh3, acc, 0, 0, 0);
      d2 = acc;
    }

    // activations + h-plane writes
    if (l1t >= 0 && s < T) {
      const float h1 = lstm_act(d1[0], d1[1], d1[2], d1[3], c1);
      if (uval1) *(_Float16*)&PL[nbuf + wbase1] = (_Float16)h1;
    }
    if (l2t >= 0 && s >= 1 && s <= T) {
      const float h2 = lstm_act(d2[0], d2[1], d2[2], d2[3], c2);
      if (uval2) *(_Float16*)&PL[nbuf + wbase2] = (_Float16)h2;
    }

    // head: out(s-2) -> OB
    if (isHead) {
      f32x4 dh = {0.f, 0.f, 0.f, 0.f};
      dh = __builtin_amdgcn_mfma_f32_16x16x32_f16(hA[0][0], bh2, dh, 0, 0, 0);
      dh = __builtin_amdgcn_mfma_f32_16x16x32_f16(hA[0][1], bh2, dh, 0, 0, 0);
      dh = __builtin_amdgcn_mfma_f32_16x16x32_f16(hA[1][0], bh3, dh, 0, 0, 0);
      dh = __builtin_amdgcn_mfma_f32_16x16x32_f16(hA[1][1], bh3, dh, 0, 0, 0);
      if (s >= 2 && s - 2 < T && lane < 16)
        OB[((s - 2) >> 5) & 1][lane][(s - 2) & 31] = dh[0];
    }
    // x(s+1) injection into next buffer
    if (isXinj && lane < 32 && s + 1 < T) {
      const int bb = lane & 15, f = lane >> 4;
      const int st = (s + 1) & 31, cb = ((s + 1) >> 5) & 1;
      const float xv = ((const float*)&XB[cb][st][0])[bb * 2 + f];
      const int idx = nbuf + 512 + ((f == 0) ? bb * 8 + 7 : (bb + 16) * 8 + 4);
      *(_Float16*)&PL[idx] = (_Float16)xv;
    }
    __syncthreads();
  }
}

extern "C" void kernel_launch(void* const* d_in, const int* in_sizes, int n_in,
                              void* d_out, int out_size, void* d_ws, size_t ws_size,
                              hipStream_t stream) {
  (void)in_sizes; (void)n_in; (void)d_ws; (void)ws_size; (void)out_size;
  const float* x    = (const float*)d_in[0];
  const float* Wih1 = (const float*)d_in[1];
  const float* Whh1 = (const float*)d_in[2];
  const float* bih1 = (const float*)d_in[3];
  const float* bhh1 = (const float*)d_in[4];
  const float* Wih2 = (const float*)d_in[5];
  const float* Whh2 = (const float*)d_in[6];
  const float* bih2 = (const float*)d_in[7];
  const float* bhh2 = (const float*)d_in[8];
  const float* Wlin = (const float*)d_in[9];
  const float* blin = (const float*)d_in[10];
  float* out = (float*)d_out;

  hipLaunchKernelGGL(lstm2_v5, dim3(GRID), dim3(BLK), 0, stream,
                     x, Wih1, Whh1, bih1, bhh1, Wih2, Whh2, bih2, bhh2,
                     Wlin, blin, out);
}